// Round 13
// baseline (263.060 us; speedup 1.0000x reference)
//
#include <hip/hip_runtime.h>
#include <hip/hip_bf16.h>

// Problem constants
#define NB   8      // batch
#define NM   288    // Bkk = 32*3*3
#define NN   1152   // Cww = 32*6*6
#define NUV  36     // w*w
#define ND   16

// ws layout (float offsets; P/Wt regions hold bf16 in half the space)
#define OFF_P    0
#define SZ_P     (NB*NUV*NM*ND)      // patches, bf16 [b][uv][m][k*4+j]
#define OFF_WT   (OFF_P + SZ_P)
#define SZ_WT    (32*NM*ND)          // W transposed, bf16 [z][m][i*4+j]
#define OFF_ACT  (OFF_WT + SZ_WT)
#define SZ_ACT   (NB*NUV*NM)         // log(act), f32 [b][uv][m]
#define OFF_L    (OFF_ACT + SZ_ACT)
#define SZ_L     (NB*NN*NM)          // ell, f32 [b][n][m] (contiguous)
#define OFF_LSE  (OFF_L + SZ_L)
#define SZ_LSE   (NB*NM)             // LSE over n, [b][m]
#define OFF_FLAG (OFF_LSE + SZ_LSE)  // dtype flag
#define OFF_PM   (OFF_FLAG + 16)
#define SZ_PM    (NB*NUV*NM)         // lse stage-1 partial max, [b][c][m]
#define OFF_PS   (OFF_PM + SZ_PM)
#define SZ_PS    (NB*NUV*NM)         // lse stage-1 partial sum, [b][c][m]

#define HALF_LOG_2PI 0.9189385332046727f
#define LOG_NN       7.049254841255839f   // log(1152)
#define NEG_BIG      (-1.0e30f)

#define CS 292   // column stride (4-float aligned -> b128-readable; 16 bank groups)

__device__ __forceinline__ float ldin(const void* p, int i, int f32) {
    return f32 ? ((const float*)p)[i]
               : __bfloat162float(((const __hip_bfloat16*)p)[i]);
}

__device__ __forceinline__ unsigned short bfbits(float f) {
    __hip_bfloat16 h = __float2bfloat16(f);
    return __builtin_bit_cast(unsigned short, h);
}

// packed bf16x2 dot with f32 accumulate: d = a.lo*b.lo + a.hi*b.hi + c
__device__ __forceinline__ float dot2bf(unsigned a, unsigned b, float c) {
    float d;
    asm("v_dot2_f32_bf16 %0, %1, %2, %3" : "=v"(d) : "v"(a), "v"(b), "v"(c));
    return d;
}

// dtype sniff (r3-r12 verified: flag==0 on this harness; kept for safety)
__global__ void detect_kernel(const unsigned short* __restrict__ poses_u16,
                              int* __restrict__ flag) {
    if (blockIdx.x == 0 && threadIdx.x == 0) {
        int wild = 0;
        for (int i = 0; i < 64; ++i) {
            int ex = (poses_u16[i] >> 7) & 0xFF;
            if (ex >= 133) ++wild;
        }
        *flag = (wild >= 4) ? 1 : 0;
    }
}

// (b,s)-tiled prep: stage poses[b,:,s,:,:] + acts[b,s,:,:] in LDS, emit bf16 P
// (uint4 stores) and f32 log(act). Blocks 256..291 transpose W (uint4 stores).
__global__ __launch_bounds__(256) void prep_kernel(
    const void* __restrict__ poses, const void* __restrict__ acts,
    const void* __restrict__ Wb, __hip_bfloat16* __restrict__ P,
    __hip_bfloat16* __restrict__ Wt, float* __restrict__ A36,
    const int* __restrict__ flagp)
{
    const int f32 = *flagp;
    const int blk = blockIdx.x;
    const int tid = threadIdx.x;
    if (blk < 256) {
        __shared__ float ps[16 * 196];
        __shared__ float asld[196];
        const int b = blk >> 5, s = blk & 31;
        for (int e = tid; e < 16 * 196; e += 256) {
            int c = e / 196, hw = e % 196;
            ps[e] = ldin(poses, ((b * 16 + c) * 32 + s) * 196 + hw, f32);
        }
        for (int e = tid; e < 196; e += 256)
            asld[e] = ldin(acts, (b * 32 + s) * 196 + e, f32);
        __syncthreads();
        // P emit: 324 rows x 2 halves; one uint4 (8 bf16) per work item
        for (int o2 = tid; o2 < 648; o2 += 256) {
            int row = o2 >> 1, half = o2 & 1;
            int uv = row / 9, xy = row % 9;
            int u = uv / 6, vv2 = uv % 6;
            int x = xy / 3, y = xy % 3;
            unsigned pk[4];
#pragma unroll
            for (int h = 0; h < 4; ++h) {
                unsigned lohi[2];
#pragma unroll
                for (int e = 0; e < 2; ++e) {
                    int kj = half * 8 + h * 2 + e;
                    int k = kj >> 2, j = kj & 3;
                    int idx = u * 96 + vv2 * 16 + j * 4 + k;   // torch view scramble
                    int c = idx / 36, rem = idx % 36;
                    int wi = rem / 6, wj = rem % 6;
                    lohi[e] = bfbits(ps[c * 196 + (2 * wi + x) * 14 + (2 * wj + y)]);
                }
                pk[h] = lohi[0] | (lohi[1] << 16);
            }
            *((uint4*)(P + (((size_t)((b * 36 + uv) * 288 + s * 9 + xy)) << 4) + half * 8)) =
                make_uint4(pk[0], pk[1], pk[2], pk[3]);
        }
        for (int o = tid; o < 324; o += 256) {
            int uv = o / 9, xy = o % 9;
            int u = uv / 6, vv2 = uv % 6;
            int x = xy / 3, y = xy % 3;
            A36[(b * 36 + uv) * 288 + s * 9 + xy] =
                __logf(asld[(2 * u + x) * 14 + (2 * vv2 + y)]);
        }
    } else {
        int idx = (blk - 256) * 256 + tid;    // 0..9215 (z,m) pairs
        int z = idx / 288, m = idx % 288;
        unsigned pk[8];
#pragma unroll
        for (int h = 0; h < 8; ++h) {
            unsigned lo = bfbits(ldin(Wb, m * 512 + z * 16 + 2 * h, f32));
            unsigned hi = bfbits(ldin(Wb, m * 512 + z * 16 + 2 * h + 1, f32));
            pk[h] = lo | (hi << 16);
        }
        uint4* dst = (uint4*)(Wt + idx * 16);
        dst[0] = make_uint4(pk[0], pk[1], pk[2], pk[3]);
        dst[1] = make_uint4(pk[4], pk[5], pk[6], pk[7]);
    }
}

// One block per (b,n) — r10 structure, ONE change (r13): the vote matrix is
// stored COLUMN-major (red[d*CS+m]) so the colsum reads its 16-m run as
// 4x ds_read_b128 (+4 broadcast b128 for Ra) instead of 32 scalar b32 reads:
// DS ops/thread 54 -> ~30 (DS pipe was the largest single consumer).
__global__ __launch_bounds__(288, 4) void em_iter(
    const unsigned short* __restrict__ wsP, const unsigned short* __restrict__ wsWt,
    const float* __restrict__ wsA, float* __restrict__ wsL,
    const float* __restrict__ wsLSE,
    const void* __restrict__ beta_v,
    const void* __restrict__ beta_a,
    const void* __restrict__ lambda_,
    void* __restrict__ outv, const int* __restrict__ flagp, int iter)
{
    __shared__ __align__(16) float red[17 * CS];  // [col][m]: 0..15 = v[d], 16 = w
    __shared__ float Mhw[9];         // per-halfwave max of t
    __shared__ float paru[NM];       // [d][c] partial sum(w*v)
    __shared__ float parv[NM];       // [d][c] partial sum(w*v*v)
    __shared__ float paruW[18];      // [c] partial sum(w)
    __shared__ float mul[16], nhil[16], ltl[16], ssl[16];

    const int tid = threadIdx.x;          // == m
    const int B   = blockIdx.x;
    const int rr  = B & 255;
    const int z   = rr >> 3;
    const int g   = ((B >> 8) << 3) | (rr & 7);   // b*36+uv
    const int b   = g / NUV;
    const int uv  = g % NUV;
    const int n   = z * NUV + uv;
    const int bn  = b * NN + n;

    // all global loads issued up front (bf16 W/P rows stay packed)
    const uint4* Wq = (const uint4*)(wsWt + ((z * NM + tid) << 4));
    const uint4* Pq = (const uint4*)(wsP + ((g * NM + tid) << 4));
    uint4 wq0 = Wq[0], wq1 = Wq[1];
    uint4 pq0 = Pq[0], pq1 = Pq[1];
    const float lact = wsA[g * NM + tid];   // pre-logged in prep
    float t;
    if (iter == 0) t = lact - LOG_NN;
    else t = wsL[(size_t)bn * NM + tid] - wsLSE[b * NM + tid] + lact;
    t = fmaxf(t, NEG_BIG);   // finite even if act==0

    // half-wave (32-lane) max via shuffles — no barrier
    float mhw = t;
#pragma unroll
    for (int off = 1; off < 32; off <<= 1)
        mhw = fmaxf(mhw, __shfl_xor(mhw, off, 32));
    const float w = __expf(t - mhw);        // per-halfwave scale; max elem = 1
    if ((tid & 31) == 0) Mhw[tid >> 5] = mhw;

    // votes v[i*4+k] = sum_j W[i][j] P[k-major][j] via packed bf16 dot2
    unsigned Wa[4]  = {wq0.x, wq0.z, wq1.x, wq1.z};   // (j0,j1) of i
    unsigned Wb_[4] = {wq0.y, wq0.w, wq1.y, wq1.w};   // (j2,j3) of i
    unsigned Pa[4]  = {pq0.x, pq0.z, pq1.x, pq1.z};   // (j0,j1) of k
    unsigned Pb[4]  = {pq0.y, pq0.w, pq1.y, pq1.w};   // (j2,j3) of k
    float v[16];
#pragma unroll
    for (int i = 0; i < 4; ++i)
#pragma unroll
        for (int k = 0; k < 4; ++k)
            v[i * 4 + k] = dot2bf(Wa[i], Pa[k], dot2bf(Wb_[i], Pb[k], 0.f));

    // transpose: column-major, lane-contiguous b32 writes (conflict-free)
#pragma unroll
    for (int dd = 0; dd < 16; ++dd) red[dd * CS + tid] = v[dd];
    red[16 * CS + tid] = w;
    __syncthreads();                                        // B1

    // column sums via b128: thread (d = tid&15, c = tid>>4) sums m = 16c..16c+15
    {
        const int d = tid & 15, c = tid >> 4;
        const float4* vcol = (const float4*)&red[d * CS + (c << 4)];
        const float4* wcol = (const float4*)&red[16 * CS + (c << 4)];
        float s1 = 0.f, s2 = 0.f, sw = 0.f;
#pragma unroll
        for (int q = 0; q < 4; ++q) {
            float4 vq = vcol[q];
            float4 wq = wcol[q];   // broadcast across the 16 d-lanes of chunk c
            float p0 = wq.x * vq.x, p1 = wq.y * vq.y;
            float p2 = wq.z * vq.z, p3 = wq.w * vq.w;
            s1 += (p0 + p1) + (p2 + p3);
            s2 += (fmaf(p0, vq.x, p1 * vq.y)) + (fmaf(p2, vq.z, p3 * vq.w));
            sw += (wq.x + wq.y) + (wq.z + wq.w);
        }
        paru[d * 18 + c] = s1;
        parv[d * 18 + c] = s2;
        if (d == 0) paruW[c] = sw;
    }
    __syncthreads();                                        // B2

    float M_f = NEG_BIG, sW_f = 0.f;   // live into the output stage (tid<16)
    if (tid < 16) {
        float M = Mhw[0];
#pragma unroll
        for (int h = 1; h < 9; ++h) M = fmaxf(M, Mhw[h]);
        float sW = 0.f, S1 = 0.f, S2 = 0.f;
#pragma unroll
        for (int c = 0; c < 18; ++c) {
            float sc = __expf(Mhw[c >> 1] - M);   // chunk c lies in halfwave c>>1
            sW += paruW[c] * sc;
            S1 += paru[tid * 18 + c] * sc;
            S2 += parv[tid * 18 + c] * sc;
        }
        float mu = S1 / sW;
        float q2 = S2 / sW;
        float ss = fmaxf(q2 - mu * mu, 1e-30f);   // E[v^2]-mu^2 (r4-r12 verified)
        mul[tid]  = mu;
        ssl[tid]  = ss;
        nhil[tid] = -0.5f / ss;
        ltl[tid]  = fmaf(-0.5f, __logf(ss), -HALF_LOG_2PI);
        M_f = M; sW_f = sW;
    }
    __syncthreads();                                        // B3

    if (iter < 3) {
        // ell[m] = log(act) + LSE_d(log_p) — serial in registers
        float lp[16];
        float M = NEG_BIG;
#pragma unroll
        for (int dd = 0; dd < 16; ++dd) {
            float df = v[dd] - mul[dd];
            lp[dd] = fmaf(df * df, nhil[dd], ltl[dd]);
            M = fmaxf(M, lp[dd]);
        }
        float s = 0.f;
#pragma unroll
        for (int dd = 0; dd < 16; ++dd) s += __expf(lp[dd] - M);
        wsL[(size_t)bn * NM + tid] = lact + M + __logf(s);   // contiguous only
    } else {
        const int f32 = *flagp;
        if (tid < 16) {
            if (f32) ((float*)outv)[(bn << 4) + tid] = mul[tid];
            else ((__hip_bfloat16*)outv)[(bn << 4) + tid] = __float2bfloat16(mul[tid]);
        }
        if (tid == 0) {
            float sumR = __expf(M_f) * sW_f;   // true sum_R (M_f <= 0)
            float bv = ldin(beta_v, n, f32);
            float c = 0.f;
#pragma unroll
            for (int dd = 0; dd < 16; ++dd) c += bv + __logf(ssl[dd]);
            c *= sumR;
            float lam = ldin(lambda_, 0, f32);
            float ba  = ldin(beta_a, n, f32);
            float ao  = 1.f / (1.f + __expf(-(lam * (ba - c))));
            int oi = NB * NN * ND + bn;
            if (f32) ((float*)outv)[oi] = ao;
            else ((__hip_bfloat16*)outv)[oi] = __float2bfloat16(ao);
        }
    }
}

// LSE stage 1: block (b,c) covers 32 rows n = 32c..32c+31 of contiguous
// L[b][n][m]; thread m walks the column (coalesced). Two passes (L2-hot).
__global__ __launch_bounds__(288) void lse1_kernel(const float* __restrict__ L,
                                                   float* __restrict__ PM,
                                                   float* __restrict__ PS)
{
    const int tid = threadIdx.x;
    const int blk = blockIdx.x;           // b*36 + c
    const int b = blk / NUV;
    const int c = blk % NUV;
    const float* base = L + ((size_t)b * NN + c * 32) * NM + tid;
    float mx = NEG_BIG;
#pragma unroll
    for (int r = 0; r < 32; ++r) mx = fmaxf(mx, base[r * NM]);
    float s = 0.f;
#pragma unroll
    for (int r = 0; r < 32; ++r) s += __expf(base[r * NM] - mx);
    PM[blk * NM + tid] = mx;
    PS[blk * NM + tid] = s;
}

// LSE stage 2: combine 36 chunk partials per (b,m) row. 2304 rows.
__global__ void lse2_kernel(const float* __restrict__ PM,
                            const float* __restrict__ PS,
                            float* __restrict__ LSE)
{
    int t = blockIdx.x * 256 + threadIdx.x;   // b*288 + m
    if (t >= NB * NM) return;
    int b = t / NM, m = t % NM;
    const float* pm = PM + (size_t)b * NUV * NM + m;
    const float* ps = PS + (size_t)b * NUV * NM + m;
    float mx = NEG_BIG;
#pragma unroll
    for (int cc = 0; cc < NUV; ++cc) mx = fmaxf(mx, pm[cc * NM]);
    float s = 0.f;
#pragma unroll
    for (int cc = 0; cc < NUV; ++cc) s += ps[cc * NM] * __expf(pm[cc * NM] - mx);
    LSE[t] = mx + __logf(s);
}

extern "C" void kernel_launch(void* const* d_in, const int* in_sizes, int n_in,
                              void* d_out, int out_size, void* d_ws, size_t ws_size,
                              hipStream_t stream)
{
    const void* poses = d_in[0];
    const void* acts  = d_in[1];
    const void* lam   = d_in[2];
    const void* Wb    = d_in[3];
    const void* bv    = d_in[4];
    const void* ba    = d_in[5];

    float* ws  = (float*)d_ws;
    __hip_bfloat16* P  = (__hip_bfloat16*)(ws + OFF_P);
    __hip_bfloat16* Wt = (__hip_bfloat16*)(ws + OFF_WT);
    float* A36 = ws + OFF_ACT;
    float* L   = ws + OFF_L;
    float* LSE = ws + OFF_LSE;
    int*  flag = (int*)(ws + OFF_FLAG);
    float* PM  = ws + OFF_PM;
    float* PS  = ws + OFF_PS;

    detect_kernel<<<1, 64, 0, stream>>>((const unsigned short*)poses, flag);

    prep_kernel<<<292, 256, 0, stream>>>(poses, acts, Wb, P, Wt, A36, flag);

    for (int it = 0; it < 4; ++it) {
        em_iter<<<NB * NN, 288, 0, stream>>>((const unsigned short*)P,
                                             (const unsigned short*)Wt,
                                             A36, L, LSE, bv, ba, lam,
                                             d_out, flag, it);
        if (it < 3) {
            lse1_kernel<<<NB * NUV, 288, 0, stream>>>(L, PM, PS);
            lse2_kernel<<<9, 256, 0, stream>>>(PM, PS, LSE);
        }
    }
}

// Round 14
// 229.773 us; speedup vs baseline: 1.1449x; 1.1449x over previous
//
#include <hip/hip_runtime.h>
#include <hip/hip_bf16.h>

// Problem constants
#define NB   8      // batch
#define NM   288    // Bkk = 32*3*3
#define NN   1152   // Cww = 32*6*6
#define NUV  36     // w*w
#define ND   16

// ws layout (float offsets; P/Wt regions hold bf16 in half the space)
#define OFF_P    0
#define SZ_P     (NB*NUV*NM*ND)      // patches, bf16 [b][uv][m][k*4+j]
#define OFF_WT   (OFF_P + SZ_P)
#define SZ_WT    (32*NM*ND)          // W transposed, bf16 [z][m][i*4+j]
#define OFF_ACT  (OFF_WT + SZ_WT)
#define SZ_ACT   (NB*NUV*NM)         // log(act), f32 [b][uv][m]
#define OFF_L    (OFF_ACT + SZ_ACT)
#define SZ_L     (NB*NN*NM)          // ell, f32 [b][n][m] (contiguous)
#define OFF_LSE  (OFF_L + SZ_L)
#define SZ_LSE   (NB*NM)             // LSE over n, [b][m]
#define OFF_FLAG (OFF_LSE + SZ_LSE)  // dtype flag
#define OFF_PM   (OFF_FLAG + 16)
#define SZ_PM    (NB*NUV*NM)         // lse stage-1 partial max, [b][c][m]
#define OFF_PS   (OFF_PM + SZ_PM)
#define SZ_PS    (NB*NUV*NM)         // lse stage-1 partial sum, [b][c][m]

#define HALF_LOG_2PI 0.9189385332046727f
#define LOG_NN       7.049254841255839f   // log(1152)
#define NEG_BIG      (-1.0e30f)

__device__ __forceinline__ float ldin(const void* p, int i, int f32) {
    return f32 ? ((const float*)p)[i]
               : __bfloat162float(((const __hip_bfloat16*)p)[i]);
}

__device__ __forceinline__ unsigned short bfbits(float f) {
    __hip_bfloat16 h = __float2bfloat16(f);
    return __builtin_bit_cast(unsigned short, h);
}

// packed bf16x2 dot with f32 accumulate: d = a.lo*b.lo + a.hi*b.hi + c
__device__ __forceinline__ float dot2bf(unsigned a, unsigned b, float c) {
    float d;
    asm("v_dot2_f32_bf16 %0, %1, %2, %3" : "=v"(d) : "v"(a), "v"(b), "v"(c));
    return d;
}

// inline dtype sniff (r3-r13 verified: flag==0 on this harness)
__device__ __forceinline__ int sniff(const unsigned short* u16) {
    int wild = 0;
    for (int i = 0; i < 64; ++i) {
        int ex = (u16[i] >> 7) & 0xFF;
        if (ex >= 133) ++wild;
    }
    return (wild >= 4) ? 1 : 0;
}

// (b,s)-tiled prep: stage poses[b,:,s,:,:] + acts[b,s,:,:] in LDS, emit bf16 P
// (uint4 stores) and f32 log(act). Blocks 256..291 transpose W (uint4 stores).
// dtype flag computed per-block inline (no separate detect launch); block 0
// publishes it for em_iter's epilogue.
__global__ __launch_bounds__(256) void prep_kernel(
    const void* __restrict__ poses, const void* __restrict__ acts,
    const void* __restrict__ Wb, __hip_bfloat16* __restrict__ P,
    __hip_bfloat16* __restrict__ Wt, float* __restrict__ A36,
    int* __restrict__ flagw)
{
    const int blk = blockIdx.x;
    const int tid = threadIdx.x;
    __shared__ int lflag;
    if (tid == 0) {
        int f = sniff((const unsigned short*)poses);
        lflag = f;
        if (blk == 0) *flagw = f;
    }
    __syncthreads();
    const int f32 = lflag;

    if (blk < 256) {
        __shared__ float ps[16 * 196];
        __shared__ float asld[196];
        const int b = blk >> 5, s = blk & 31;
        for (int e = tid; e < 16 * 196; e += 256) {
            int c = e / 196, hw = e % 196;
            ps[e] = ldin(poses, ((b * 16 + c) * 32 + s) * 196 + hw, f32);
        }
        for (int e = tid; e < 196; e += 256)
            asld[e] = ldin(acts, (b * 32 + s) * 196 + e, f32);
        __syncthreads();
        // P emit: 324 rows x 2 halves; one uint4 (8 bf16) per work item
        for (int o2 = tid; o2 < 648; o2 += 256) {
            int row = o2 >> 1, half = o2 & 1;
            int uv = row / 9, xy = row % 9;
            int u = uv / 6, vv2 = uv % 6;
            int x = xy / 3, y = xy % 3;
            unsigned pk[4];
#pragma unroll
            for (int h = 0; h < 4; ++h) {
                unsigned lohi[2];
#pragma unroll
                for (int e = 0; e < 2; ++e) {
                    int kj = half * 8 + h * 2 + e;
                    int k = kj >> 2, j = kj & 3;
                    int idx = u * 96 + vv2 * 16 + j * 4 + k;   // torch view scramble
                    int c = idx / 36, rem = idx % 36;
                    int wi = rem / 6, wj = rem % 6;
                    lohi[e] = bfbits(ps[c * 196 + (2 * wi + x) * 14 + (2 * wj + y)]);
                }
                pk[h] = lohi[0] | (lohi[1] << 16);
            }
            *((uint4*)(P + (((size_t)((b * 36 + uv) * 288 + s * 9 + xy)) << 4) + half * 8)) =
                make_uint4(pk[0], pk[1], pk[2], pk[3]);
        }
        for (int o = tid; o < 324; o += 256) {
            int uv = o / 9, xy = o % 9;
            int u = uv / 6, vv2 = uv % 6;
            int x = xy / 3, y = xy % 3;
            A36[(b * 36 + uv) * 288 + s * 9 + xy] =
                __logf(asld[(2 * u + x) * 14 + (2 * vv2 + y)]);
        }
    } else {
        int idx = (blk - 256) * 256 + tid;    // 0..9215 (z,m) pairs
        int z = idx / 288, m = idx % 288;
        unsigned pk[8];
#pragma unroll
        for (int h = 0; h < 8; ++h) {
            unsigned lo = bfbits(ldin(Wb, m * 512 + z * 16 + 2 * h, f32));
            unsigned hi = bfbits(ldin(Wb, m * 512 + z * 16 + 2 * h + 1, f32));
            pk[h] = lo | (hi << 16);
        }
        uint4* dst = (uint4*)(Wt + idx * 16);
        dst[0] = make_uint4(pk[0], pk[1], pk[2], pk[3]);
        dst[1] = make_uint4(pk[4], pk[5], pk[6], pk[7]);
    }
}

// One block per (b,n) — r10 structure verbatim (best-known-good: 43.2 µs,
// 0 bank conflicts, FETCH 7.9 MB). m-major stride-17 transpose; b32 colsum.
// XCD swizzle: blockIdx = (g>>3)*256 + z*8 + (g&7), g = b*36+uv.
__global__ __launch_bounds__(288, 4) void em_iter(
    const unsigned short* __restrict__ wsP, const unsigned short* __restrict__ wsWt,
    const float* __restrict__ wsA, float* __restrict__ wsL,
    const float* __restrict__ wsLSE,
    const void* __restrict__ beta_v,
    const void* __restrict__ beta_a,
    const void* __restrict__ lambda_,
    void* __restrict__ outv, const int* __restrict__ flagp, int iter)
{
    __shared__ float red[NM * 17];   // [m][col]: 0..15 = v[d], 16 = w  (19.6 KB)
    __shared__ float Mhw[9];         // per-halfwave max of t
    __shared__ float paru[NM];       // [d][c] partial sum(w*v)
    __shared__ float parv[NM];       // [d][c] partial sum(w*v*v)
    __shared__ float paruW[18];      // [c] partial sum(w)
    __shared__ float mul[16], nhil[16], ltl[16], ssl[16];

    const int tid = threadIdx.x;          // == m
    const int B   = blockIdx.x;
    const int rr  = B & 255;
    const int z   = rr >> 3;
    const int g   = ((B >> 8) << 3) | (rr & 7);   // b*36+uv
    const int b   = g / NUV;
    const int uv  = g % NUV;
    const int n   = z * NUV + uv;
    const int bn  = b * NN + n;

    // all global loads issued up front (bf16 W/P rows stay packed)
    const uint4* Wq = (const uint4*)(wsWt + ((z * NM + tid) << 4));
    const uint4* Pq = (const uint4*)(wsP + ((g * NM + tid) << 4));
    uint4 wq0 = Wq[0], wq1 = Wq[1];
    uint4 pq0 = Pq[0], pq1 = Pq[1];
    const float lact = wsA[g * NM + tid];   // pre-logged in prep
    float t;
    if (iter == 0) t = lact - LOG_NN;
    else t = wsL[(size_t)bn * NM + tid] - wsLSE[b * NM + tid] + lact;
    t = fmaxf(t, NEG_BIG);   // finite even if act==0

    // half-wave (32-lane) max via shuffles — no barrier
    float mhw = t;
#pragma unroll
    for (int off = 1; off < 32; off <<= 1)
        mhw = fmaxf(mhw, __shfl_xor(mhw, off, 32));
    const float w = __expf(t - mhw);        // per-halfwave scale; max elem = 1
    if ((tid & 31) == 0) Mhw[tid >> 5] = mhw;

    // votes v[i*4+k] = sum_j W[i][j] P[k-major][j] via packed bf16 dot2
    unsigned Wa[4]  = {wq0.x, wq0.z, wq1.x, wq1.z};   // (j0,j1) of i
    unsigned Wb_[4] = {wq0.y, wq0.w, wq1.y, wq1.w};   // (j2,j3) of i
    unsigned Pa[4]  = {pq0.x, pq0.z, pq1.x, pq1.z};   // (j0,j1) of k
    unsigned Pb[4]  = {pq0.y, pq0.w, pq1.y, pq1.w};   // (j2,j3) of k
    float v[16];
#pragma unroll
    for (int i = 0; i < 4; ++i)
#pragma unroll
        for (int k = 0; k < 4; ++k)
            v[i * 4 + k] = dot2bf(Wa[i], Pa[k], dot2bf(Wb_[i], Pb[k], 0.f));

    // transpose: m-major stride 17 (odd -> bank-bijective, 2-way = free)
#pragma unroll
    for (int dd = 0; dd < 16; ++dd) red[tid * 17 + dd] = v[dd];
    red[tid * 17 + 16] = w;
    __syncthreads();                                        // B1

    // column sums: thread (d = tid&15, c = tid>>4) sums m = 16c..16c+15
    {
        const int d = tid & 15, c = tid >> 4;
        const float* base = &red[(c << 4) * 17];
        float s1 = 0.f, s2 = 0.f, sw = 0.f;
#pragma unroll
        for (int q = 0; q < 16; ++q) {
            float ww = base[q * 17 + 16];
            float vv = base[q * 17 + d];
            float t1 = ww * vv;
            s1 += t1; s2 += t1 * vv; sw += ww;
        }
        paru[d * 18 + c] = s1;
        parv[d * 18 + c] = s2;
        if (d == 0) paruW[c] = sw;
    }
    __syncthreads();                                        // B2

    float M_f = NEG_BIG, sW_f = 0.f;   // live into the output stage (tid<16)
    if (tid < 16) {
        float M = Mhw[0];
#pragma unroll
        for (int h = 1; h < 9; ++h) M = fmaxf(M, Mhw[h]);
        float sW = 0.f, S1 = 0.f, S2 = 0.f;
#pragma unroll
        for (int c = 0; c < 18; ++c) {
            float sc = __expf(Mhw[c >> 1] - M);   // chunk c lies in halfwave c>>1
            sW += paruW[c] * sc;
            S1 += paru[tid * 18 + c] * sc;
            S2 += parv[tid * 18 + c] * sc;
        }
        float mu = S1 / sW;
        float q2 = S2 / sW;
        float ss = fmaxf(q2 - mu * mu, 1e-30f);   // E[v^2]-mu^2 (r4-r13 verified)
        mul[tid]  = mu;
        ssl[tid]  = ss;
        nhil[tid] = -0.5f / ss;
        ltl[tid]  = fmaf(-0.5f, __logf(ss), -HALF_LOG_2PI);
        M_f = M; sW_f = sW;
    }
    __syncthreads();                                        // B3

    if (iter < 3) {
        // ell[m] = log(act) + LSE_d(log_p) — serial in registers
        float lp[16];
        float M = NEG_BIG;
#pragma unroll
        for (int dd = 0; dd < 16; ++dd) {
            float df = v[dd] - mul[dd];
            lp[dd] = fmaf(df * df, nhil[dd], ltl[dd]);
            M = fmaxf(M, lp[dd]);
        }
        float s = 0.f;
#pragma unroll
        for (int dd = 0; dd < 16; ++dd) s += __expf(lp[dd] - M);
        wsL[(size_t)bn * NM + tid] = lact + M + __logf(s);   // contiguous only
    } else {
        const int f32 = *flagp;
        if (tid < 16) {
            if (f32) ((float*)outv)[(bn << 4) + tid] = mul[tid];
            else ((__hip_bfloat16*)outv)[(bn << 4) + tid] = __float2bfloat16(mul[tid]);
        }
        if (tid == 0) {
            float sumR = __expf(M_f) * sW_f;   // true sum_R (M_f <= 0)
            float bv = ldin(beta_v, n, f32);
            float c = 0.f;
#pragma unroll
            for (int dd = 0; dd < 16; ++dd) c += bv + __logf(ssl[dd]);
            c *= sumR;
            float lam = ldin(lambda_, 0, f32);
            float ba  = ldin(beta_a, n, f32);
            float ao  = 1.f / (1.f + __expf(-(lam * (ba - c))));
            int oi = NB * NN * ND + bn;
            if (f32) ((float*)outv)[oi] = ao;
            else ((__hip_bfloat16*)outv)[oi] = __float2bfloat16(ao);
        }
    }
}

// LSE stage 1: block (b,c) covers 32 rows n = 32c..32c+31 of contiguous
// L[b][n][m]; thread m walks the column (coalesced). Two passes (L2-hot).
__global__ __launch_bounds__(288) void lse1_kernel(const float* __restrict__ L,
                                                   float* __restrict__ PM,
                                                   float* __restrict__ PS)
{
    const int tid = threadIdx.x;
    const int blk = blockIdx.x;           // b*36 + c
    const int b = blk / NUV;
    const int c = blk % NUV;
    const float* base = L + ((size_t)b * NN + c * 32) * NM + tid;
    float mx = NEG_BIG;
#pragma unroll
    for (int r = 0; r < 32; ++r) mx = fmaxf(mx, base[r * NM]);
    float s = 0.f;
#pragma unroll
    for (int r = 0; r < 32; ++r) s += __expf(base[r * NM] - mx);
    PM[blk * NM + tid] = mx;
    PS[blk * NM + tid] = s;
}

// LSE stage 2: combine 36 chunk partials per (b,m) row. 2304 rows.
__global__ void lse2_kernel(const float* __restrict__ PM,
                            const float* __restrict__ PS,
                            float* __restrict__ LSE)
{
    int t = blockIdx.x * 256 + threadIdx.x;   // b*288 + m
    if (t >= NB * NM) return;
    int b = t / NM, m = t % NM;
    const float* pm = PM + (size_t)b * NUV * NM + m;
    const float* ps = PS + (size_t)b * NUV * NM + m;
    float mx = NEG_BIG;
#pragma unroll
    for (int cc = 0; cc < NUV; ++cc) mx = fmaxf(mx, pm[cc * NM]);
    float s = 0.f;
#pragma unroll
    for (int cc = 0; cc < NUV; ++cc) s += ps[cc * NM] * __expf(pm[cc * NM] - mx);
    LSE[t] = mx + __logf(s);
}

extern "C" void kernel_launch(void* const* d_in, const int* in_sizes, int n_in,
                              void* d_out, int out_size, void* d_ws, size_t ws_size,
                              hipStream_t stream)
{
    const void* poses = d_in[0];
    const void* acts  = d_in[1];
    const void* lam   = d_in[2];
    const void* Wb    = d_in[3];
    const void* bv    = d_in[4];
    const void* ba    = d_in[5];

    float* ws  = (float*)d_ws;
    __hip_bfloat16* P  = (__hip_bfloat16*)(ws + OFF_P);
    __hip_bfloat16* Wt = (__hip_bfloat16*)(ws + OFF_WT);
    float* A36 = ws + OFF_ACT;
    float* L   = ws + OFF_L;
    float* LSE = ws + OFF_LSE;
    int*  flag = (int*)(ws + OFF_FLAG);
    float* PM  = ws + OFF_PM;
    float* PS  = ws + OFF_PS;

    prep_kernel<<<292, 256, 0, stream>>>(poses, acts, Wb, P, Wt, A36, flag);

    for (int it = 0; it < 4; ++it) {
        em_iter<<<NB * NN, 288, 0, stream>>>((const unsigned short*)P,
                                             (const unsigned short*)Wt,
                                             A36, L, LSE, bv, ba, lam,
                                             d_out, flag, it);
        if (it < 3) {
            lse1_kernel<<<NB * NUV, 288, 0, stream>>>(L, PM, PS);
            lse2_kernel<<<9, 256, 0, stream>>>(PM, PS, LSE);
        }
    }
}